// Round 6
// baseline (296.645 us; speedup 1.0000x reference)
//
#include <hip/hip_runtime.h>

#define NCLS   18
#define TROWS  128                      // rows per wave-tile (B = 2,000,000 = 128 * 15625)
#define TWORDS (TROWS * NCLS)           // 2304 floats = 9216 B per array per tile
#define NF4    (TWORDS / 4)             // 576 float4 per array per tile

#define REP9(F) F(0) F(1) F(2) F(3) F(4) F(5) F(6) F(7) F(8)

// ---- per-tile compute from wave-private LDS slice (macro: nothing address-takeable) ----
#define COMPUTE_TILE()                                                                   \
  do {                                                                                   \
    const float4* rx = bufX + lane * 9;   /* lane owns rows 2*lane, 2*lane+1 (144 B) */  \
    float4 v0 = rx[0], v1 = rx[1], v2 = rx[2], v3 = rx[3], v4 = rx[4],                   \
           v5 = rx[5], v6 = rx[6], v7 = rx[7], v8 = rx[8];                               \
    float mA = fmaxf(fmaxf(fmaxf(v0.x, v0.y), fmaxf(v0.z, v0.w)),                        \
               fmaxf(fmaxf(fmaxf(v1.x, v1.y), fmaxf(v1.z, v1.w)),                        \
               fmaxf(fmaxf(fmaxf(v2.x, v2.y), fmaxf(v2.z, v2.w)),                        \
               fmaxf(fmaxf(fmaxf(v3.x, v3.y), fmaxf(v3.z, v3.w)),                        \
                     fmaxf(v4.x, v4.y)))));                                              \
    float mB = fmaxf(fmaxf(fmaxf(v5.x, v5.y), fmaxf(v5.z, v5.w)),                        \
               fmaxf(fmaxf(fmaxf(v6.x, v6.y), fmaxf(v6.z, v6.w)),                        \
               fmaxf(fmaxf(fmaxf(v7.x, v7.y), fmaxf(v7.z, v7.w)),                        \
               fmaxf(fmaxf(fmaxf(v8.x, v8.y), fmaxf(v8.z, v8.w)),                        \
                     fmaxf(v4.z, v4.w)))));                                              \
    float seA = __expf(v0.x-mA)+__expf(v0.y-mA)+__expf(v0.z-mA)+__expf(v0.w-mA)          \
              + __expf(v1.x-mA)+__expf(v1.y-mA)+__expf(v1.z-mA)+__expf(v1.w-mA)          \
              + __expf(v2.x-mA)+__expf(v2.y-mA)+__expf(v2.z-mA)+__expf(v2.w-mA)          \
              + __expf(v3.x-mA)+__expf(v3.y-mA)+__expf(v3.z-mA)+__expf(v3.w-mA)          \
              + __expf(v4.x-mA)+__expf(v4.y-mA);                                         \
    float seB = __expf(v4.z-mB)+__expf(v4.w-mB)                                          \
              + __expf(v5.x-mB)+__expf(v5.y-mB)+__expf(v5.z-mB)+__expf(v5.w-mB)          \
              + __expf(v6.x-mB)+__expf(v6.y-mB)+__expf(v6.z-mB)+__expf(v6.w-mB)          \
              + __expf(v7.x-mB)+__expf(v7.y-mB)+__expf(v7.z-mB)+__expf(v7.w-mB)          \
              + __expf(v8.x-mB)+__expf(v8.y-mB)+__expf(v8.z-mB)+__expf(v8.w-mB);         \
    float lseA = mA + __logf(seA);                                                       \
    float lseB = mB + __logf(seB);                                                       \
    const float4* rl = bufL + lane * 9;                                                  \
    float4 w;                                                                            \
    w = rl[0];                                                                           \
    acc = fmaf(w.x, lseA - v0.x, acc); acc = fmaf(w.y, lseA - v0.y, acc);                \
    acc = fmaf(w.z, lseA - v0.z, acc); acc = fmaf(w.w, lseA - v0.w, acc);                \
    w = rl[1];                                                                           \
    acc = fmaf(w.x, lseA - v1.x, acc); acc = fmaf(w.y, lseA - v1.y, acc);                \
    acc = fmaf(w.z, lseA - v1.z, acc); acc = fmaf(w.w, lseA - v1.w, acc);                \
    w = rl[2];                                                                           \
    acc = fmaf(w.x, lseA - v2.x, acc); acc = fmaf(w.y, lseA - v2.y, acc);                \
    acc = fmaf(w.z, lseA - v2.z, acc); acc = fmaf(w.w, lseA - v2.w, acc);                \
    w = rl[3];                                                                           \
    acc = fmaf(w.x, lseA - v3.x, acc); acc = fmaf(w.y, lseA - v3.y, acc);                \
    acc = fmaf(w.z, lseA - v3.z, acc); acc = fmaf(w.w, lseA - v3.w, acc);                \
    w = rl[4];                                                                           \
    acc = fmaf(w.x, lseA - v4.x, acc); acc = fmaf(w.y, lseA - v4.y, acc);                \
    acc = fmaf(w.z, lseB - v4.z, acc); acc = fmaf(w.w, lseB - v4.w, acc);                \
    w = rl[5];                                                                           \
    acc = fmaf(w.x, lseB - v5.x, acc); acc = fmaf(w.y, lseB - v5.y, acc);                \
    acc = fmaf(w.z, lseB - v5.z, acc); acc = fmaf(w.w, lseB - v5.w, acc);                \
    w = rl[6];                                                                           \
    acc = fmaf(w.x, lseB - v6.x, acc); acc = fmaf(w.y, lseB - v6.y, acc);                \
    acc = fmaf(w.z, lseB - v6.z, acc); acc = fmaf(w.w, lseB - v6.w, acc);                \
    w = rl[7];                                                                           \
    acc = fmaf(w.x, lseB - v7.x, acc); acc = fmaf(w.y, lseB - v7.y, acc);                \
    acc = fmaf(w.z, lseB - v7.z, acc); acc = fmaf(w.w, lseB - v7.w, acc);                \
    w = rl[8];                                                                           \
    acc = fmaf(w.x, lseB - v8.x, acc); acc = fmaf(w.y, lseB - v8.y, acc);                \
    acc = fmaf(w.z, lseB - v8.z, acc); acc = fmaf(w.w, lseB - v8.w, acc);                \
  } while (0)

// launch_bounds(256, 2): LDS already caps us at 2 blocks/CU (= 2 waves/EU), so
// declaring it costs nothing and raises the VGPR budget to 256/wave — the round-5
// allocator squeezed prefetch into 88 VGPRs and serialized the loads.
__global__ __launch_bounds__(256, 2) void ce_soft_main(
    const float* __restrict__ logits,
    const float* __restrict__ labels,
    float* __restrict__ partial,
    int B)
{
    // wave-private LDS slices: 4 waves x (9216 X + 9216 L) = 73728 B -> 2 blocks/CU
    __shared__ float4 sX[4][NF4];
    __shared__ float4 sL[4][NF4];
    __shared__ float sWS[4];

    const int tid  = threadIdx.x;
    const int lane = tid & 63;
    const int wid  = tid >> 6;
    float4* bufX = &sX[wid][0];
    float4* bufL = &sL[wid][0];

    const int nTiles  = B / TROWS;             // 15625
    const int wgid    = blockIdx.x * 4 + wid;  // global wave id
    const int wstride = gridDim.x * 4;         // 2048 waves

    float acc = 0.0f;

    // ---- two named prefetch register sets: 2 tiles deep, 144 VGPRs, no arrays ----
#define DECLP(i) float4 Ax##i, Al##i, Bx##i, Bl##i;
    REP9(DECLP)
#undef DECLP

#define LOADA(i) Ax##i = gx[64 * i]; Al##i = gl[64 * i];
#define LOADB(i) Bx##i = gx[64 * i]; Bl##i = gl[64 * i];

    // prologue: A <- tile wgid, B <- tile wgid + wstride
    if (wgid < nTiles) {
        const float4* gx = (const float4*)(logits + (size_t)wgid * TWORDS) + lane;
        const float4* gl = (const float4*)(labels + (size_t)wgid * TWORDS) + lane;
        REP9(LOADA)
    }
    if (wgid + wstride < nTiles) {
        const float4* gx = (const float4*)(logits + (size_t)(wgid + wstride) * TWORDS) + lane;
        const float4* gl = (const float4*)(labels + (size_t)(wgid + wstride) * TWORDS) + lane;
        REP9(LOADB)
    }

    // ---- main loop: 2 tiles/iter, zero __syncthreads, per-wave counted waits only ----
    for (int t = wgid; t < nTiles; t += 2 * wstride) {
        // tile t from set A: stage -> refill A (2 tiles ahead) -> compute
#define STXA(i) bufX[64 * i + lane] = Ax##i;
#define STLA(i) bufL[64 * i + lane] = Al##i;
        REP9(STXA)
        REP9(STLA)
#undef STXA
#undef STLA
        {
            int tn = t + 2 * wstride;
            if (tn < nTiles) {
                const float4* gx = (const float4*)(logits + (size_t)tn * TWORDS) + lane;
                const float4* gl = (const float4*)(labels + (size_t)tn * TWORDS) + lane;
                REP9(LOADA)
            }
        }
        COMPUTE_TILE();

        // tile t + wstride from set B
        int t1 = t + wstride;
        if (t1 < nTiles) {
#define STXB(i) bufX[64 * i + lane] = Bx##i;
#define STLB(i) bufL[64 * i + lane] = Bl##i;
            REP9(STXB)
            REP9(STLB)
#undef STXB
#undef STLB
            {
                int tn = t1 + 2 * wstride;
                if (tn < nTiles) {
                    const float4* gx = (const float4*)(logits + (size_t)tn * TWORDS) + lane;
                    const float4* gl = (const float4*)(labels + (size_t)tn * TWORDS) + lane;
                    REP9(LOADB)
                }
            }
            COMPUTE_TILE();
        }
    }
#undef LOADA
#undef LOADB

    // generic tail (B % TROWS != 0) — empty for B = 2,000,000
    for (int row = nTiles * TROWS + blockIdx.x * blockDim.x + tid; row < B;
         row += gridDim.x * blockDim.x) {
        const float2* o2 = (const float2*)(logits + (size_t)row * NCLS);
        const float2* l2 = (const float2*)(labels + (size_t)row * NCLS);
        float x[NCLS], l[NCLS];
        #pragma unroll
        for (int k = 0; k < NCLS / 2; ++k) {
            float2 v = o2[k]; x[2 * k] = v.x; x[2 * k + 1] = v.y;
            float2 w = l2[k]; l[2 * k] = w.x; l[2 * k + 1] = w.y;
        }
        float mm = x[0];
        #pragma unroll
        for (int c = 1; c < NCLS; ++c) mm = fmaxf(mm, x[c]);
        float se = 0.f, dot = 0.f, sl = 0.f;
        #pragma unroll
        for (int c = 0; c < NCLS; ++c) {
            se += __expf(x[c] - mm);
            dot = fmaf(l[c], x[c], dot);
            sl += l[c];
        }
        acc = fmaf(sl, mm + __logf(se), acc - dot);
    }

    // block reduction -> plain store of partial (no atomic, no memset)
    #pragma unroll
    for (int off = 32; off > 0; off >>= 1)
        acc += __shfl_down(acc, off, 64);
    if (lane == 0) sWS[wid] = acc;
    __syncthreads();
    if (tid == 0)
        partial[blockIdx.x] = sWS[0] + sWS[1] + sWS[2] + sWS[3];
}

__global__ __launch_bounds__(256) void ce_soft_finish(
    const float* __restrict__ partial, float* __restrict__ result,
    int n, float invB)
{
    float s = 0.f;
    for (int i = threadIdx.x; i < n; i += 256) s += partial[i];
    #pragma unroll
    for (int off = 32; off > 0; off >>= 1)
        s += __shfl_down(s, off, 64);
    __shared__ float ws[4];
    int lane = threadIdx.x & 63, wid = threadIdx.x >> 6;
    if (lane == 0) ws[wid] = s;
    __syncthreads();
    if (threadIdx.x == 0)
        result[0] = (ws[0] + ws[1] + ws[2] + ws[3]) * invB;  // plain store overwrites poison
}

extern "C" void kernel_launch(void* const* d_in, const int* in_sizes, int n_in,
                              void* d_out, int out_size, void* d_ws, size_t ws_size,
                              hipStream_t stream) {
    const float* logits = (const float*)d_in[0];
    const float* labels = (const float*)d_in[1];
    float* result = (float*)d_out;

    int B = in_sizes[0] / NCLS;            // 2,000,000

    // grid = 512: 2 blocks/CU (LDS-capped, 73.7 KiB/block) x 256 CU = exactly resident
    int grid = 512;
    if (ws_size < (size_t)grid * sizeof(float)) {
        grid = (int)(ws_size / sizeof(float));
        if (grid > 512) grid = 512;
        if (grid < 1) grid = 1;
    }
    float* partial = (float*)d_ws;

    ce_soft_main<<<grid, 256, 0, stream>>>(logits, labels, partial, B);
    ce_soft_finish<<<1, 256, 0, stream>>>(partial, result, grid, 1.0f / (float)B);
}